// Round 1
// baseline (230.171 us; speedup 1.0000x reference)
//
#include <hip/hip_runtime.h>

// B=4, S=4096, D_IN=1024, D_QK=D_V=64
// out = softmax(relu(XWq+bq) @ relu(XWk+bk)^T) @ relu(XWv+bv) * mask

typedef short s16x8 __attribute__((ext_vector_type(8)));   // 8 bf16 (4 VGPRs) MFMA frag
typedef float fx4   __attribute__((ext_vector_type(4)));   // MFMA accum frag
typedef unsigned short u16x4 __attribute__((ext_vector_type(4)));

#define LOG2E 1.4426950408889634f

__device__ __forceinline__ unsigned short f2bf(float x) {   // fp32 -> bf16 RTN
    unsigned int u = __float_as_uint(x);
    u += 0x7FFFu + ((u >> 16) & 1u);
    return (unsigned short)(u >> 16);
}
__device__ __forceinline__ float bf2f(unsigned short b) {
    return __uint_as_float(((unsigned int)b) << 16);
}

// ---------------------------------------------------------------------------
// Kernel 1: split W{q,k,v} [1024][64] fp32 into W^T hi/lo bf16 [3][64][1024].
// LDS tile-transpose; coalesced reads, contiguous 32 B runs along k going out.
// grid (3 y, 16 k-tiles) x 256.  (unchanged)
// ---------------------------------------------------------------------------
__global__ __launch_bounds__(256) void prep_w_kernel(
    const float* __restrict__ Wq, const float* __restrict__ Wk, const float* __restrict__ Wv,
    unsigned short* __restrict__ wt_hi, unsigned short* __restrict__ wt_lo)
{
    __shared__ __align__(16) unsigned short sh[64][72];   // [c][k_local]
    __shared__ __align__(16) unsigned short sl[64][72];

    const int y  = blockIdx.x;
    const int kt = blockIdx.y;
    const float* W = (y == 0) ? Wq : (y == 1) ? Wk : Wv;
    const int t  = threadIdx.x;

    const int kl = t >> 2;
    const int c0 = (t & 3) * 16;
    const float* src = W + (size_t)(kt * 64 + kl) * 64 + c0;
    #pragma unroll
    for (int j = 0; j < 4; j++) {
        fx4 v = *(const fx4*)(src + j * 4);
        #pragma unroll
        for (int i = 0; i < 4; i++) {
            float x = v[i];
            unsigned short h = f2bf(x);
            unsigned short l = f2bf(x - bf2f(h));
            sh[c0 + j * 4 + i][kl] = h;
            sl[c0 + j * 4 + i][kl] = l;
        }
    }
    __syncthreads();

    const int c  = t >> 2;
    const int k0 = (t & 3) * 16;
    size_t o = (size_t)(y * 64 + c) * 1024 + kt * 64 + k0;
    *(s16x8*)(wt_hi + o)     = *(const s16x8*)&sh[c][k0];
    *(s16x8*)(wt_hi + o + 8) = *(const s16x8*)&sh[c][k0 + 8];
    *(s16x8*)(wt_lo + o)     = *(const s16x8*)&sl[c][k0];
    *(s16x8*)(wt_lo + o + 8) = *(const s16x8*)&sl[c][k0 + 8];
}

// ---------------------------------------------------------------------------
// Kernel 2 (v3): projection. 1D grid 768, XCD-swizzled (3 y-blocks sharing an
// X m-tile land on the same XCD). Block 512 (8 waves = 4 row-subtiles x 2
// col-halves), M-tile 64.
// v3 change vs v2: the old version round-tripped the W tile through LDS,
// putting 2/3 of the per-kc LDS read volume (the saturated pipe: 288KB
// reads + 48KB writes per CU-kc ~ the whole 2350cy/kc budget at ~112B/cy)
// on data that is L2-resident and shared by 256 blocks. Now B-frags are
// loaded straight from global (wt_hi/wt_lo): 100% cacheline utilization
// (ks=0/1 cover both 64B halves of each row's 128B kc-line), 4x intra-block
// L1 reuse (same-ch waves read identical addresses). LDS holds only the
// X tile, double-buffered -> ONE barrier per kc instead of two. LDS total
// stays 36864B. MFMA order (hh,hl,lh per nt,ks) and f2bf rounding are
// bit-identical to v2 => identical outputs.
// ---------------------------------------------------------------------------
__global__ __launch_bounds__(512, 6) void proj_kernel(
    const float* __restrict__ X,
    const unsigned short* __restrict__ wt_hi, const unsigned short* __restrict__ wt_lo,
    const float* __restrict__ bq, const float* __restrict__ bk, const float* __restrict__ bv,
    unsigned short* __restrict__ q_hi, unsigned short* __restrict__ q_lo,
    unsigned short* __restrict__ k_bf, unsigned short* __restrict__ vt_g)
{
    // [dbuf][hi/lo][row][col], +8 pad: row stride 144B => 2-way bank alias (free)
    __shared__ __align__(16) unsigned short a_buf[2][2][64][72];

    const int tid  = threadIdx.x;
    const int lane = tid & 63;
    const int w    = tid >> 6;      // 0..7
    const int quad = lane >> 4;
    const int l15  = lane & 15;
    const int rs   = w & 3;         // row-subtile (16 rows)
    const int ch   = w >> 2;        // col half (32 cols)

    // XCD swizzle decode: f = (m & 7) + 8*(y + 3*(m >> 3))
    const int f   = blockIdx.x;
    const int xcd = f & 7;
    const int jj  = f >> 3;
    const int y   = jj % 3;         // 0=q 1=k 2=v
    const int m0  = ((jj / 3) * 8 + xcd) * 64;

    fx4 acc[2];
    acc[0] = (fx4){0.f, 0.f, 0.f, 0.f};
    acc[1] = (fx4){0.f, 0.f, 0.f, 0.f};

    const int xrow = tid >> 4;        // 0..31
    const int xoff = (tid & 15) * 4;

    const float* xb0 = X + (size_t)(m0 + xrow) * 1024 + xoff;
    const float* xb1 = X + (size_t)(m0 + xrow + 32) * 1024 + xoff;

    // per-lane W-frag base pointers (row = y*64 + ch*32 + nt*16 + l15, +quad*8)
    const size_t wb = (size_t)(y * 64 + ch * 32 + l15) * 1024 + quad * 8;
    const unsigned short* wph0 = wt_hi + wb;
    const unsigned short* wph1 = wph0 + 16 * 1024;
    const unsigned short* wpl0 = wt_lo + wb;
    const unsigned short* wpl1 = wpl0 + 16 * 1024;

    const int arow = rs * 16 + l15;   // A-frag row
    const int acol = quad * 8;        // A-frag col base

    // convert one X chunk (2 fx4/thread) to hi/lo bf16 and stage into buf d
    auto cvt_store = [&](int d, fx4 va, fx4 vb) {
        #pragma unroll
        for (int i = 0; i < 2; i++) {
            fx4 xv = i ? vb : va;
            unsigned short h0 = f2bf(xv.x), h1 = f2bf(xv.y), h2 = f2bf(xv.z), h3 = f2bf(xv.w);
            unsigned short l0 = f2bf(xv.x - bf2f(h0)), l1 = f2bf(xv.y - bf2f(h1));
            unsigned short l2 = f2bf(xv.z - bf2f(h2)), l3 = f2bf(xv.w - bf2f(h3));
            *(u16x4*)&a_buf[d][0][xrow + i * 32][xoff] = (u16x4){h0, h1, h2, h3};
            *(u16x4*)&a_buf[d][1][xrow + i * 32][xoff] = (u16x4){l0, l1, l2, l3};
        }
    };

    // prologue: chunk 0 -> buf0; preload chunks 1 (slot1) and 2 (slot0)
    fx4 xr[2][2];
    cvt_store(0, *(const fx4*)(xb0), *(const fx4*)(xb1));
    xr[1][0] = *(const fx4*)(xb0 + 64);
    xr[1][1] = *(const fx4*)(xb1 + 64);
    xr[0][0] = *(const fx4*)(xb0 + 128);
    xr[0][1] = *(const fx4*)(xb1 + 128);
    __syncthreads();

    #pragma unroll
    for (int kc = 0; kc < 16; kc++) {
        const int cur = kc & 1;
        // stage chunk kc+1 into the other buffer (its readers of the PREVIOUS
        // occupancy of that buffer finished before last iteration's barrier)
        if (kc < 15) cvt_store(cur ^ 1, xr[(kc + 1) & 1][0], xr[(kc + 1) & 1][1]);
        // refill slot with chunk kc+3 (consumed at iter kc+2)
        if (kc < 13) {
            xr[(kc + 1) & 1][0] = *(const fx4*)(xb0 + (kc + 3) * 64);
            xr[(kc + 1) & 1][1] = *(const fx4*)(xb1 + (kc + 3) * 64);
        }
        // A frags from LDS (one addr reg + immediate offsets)
        s16x8 ah[2], al[2];
        #pragma unroll
        for (int ks = 0; ks < 2; ks++) {
            ah[ks] = *(const s16x8*)&a_buf[cur][0][arow][ks * 32 + acol];
            al[ks] = *(const s16x8*)&a_buf[cur][1][arow][ks * 32 + acol];
        }
        // B frags direct from global (L1/L2), same values the LDS tile held
        #pragma unroll
        for (int nt = 0; nt < 2; nt++) {
            const unsigned short* ph = nt ? wph1 : wph0;
            const unsigned short* pl = nt ? wpl1 : wpl0;
            #pragma unroll
            for (int ks = 0; ks < 2; ks++) {
                s16x8 bh = *(const s16x8*)(ph + kc * 64 + ks * 32);
                s16x8 bl = *(const s16x8*)(pl + kc * 64 + ks * 32);
                acc[nt] = __builtin_amdgcn_mfma_f32_16x16x32_bf16(ah[ks], bh, acc[nt], 0, 0, 0);
                acc[nt] = __builtin_amdgcn_mfma_f32_16x16x32_bf16(ah[ks], bl, acc[nt], 0, 0, 0);
                acc[nt] = __builtin_amdgcn_mfma_f32_16x16x32_bf16(al[ks], bh, acc[nt], 0, 0, 0);
            }
        }
        __syncthreads();   // staged buffer ready for next iter; readers drained
    }

    // epilogue: bias + relu, write per-matrix (final loop barrier already
    // guarantees all LDS frag reads are done before vtr alias writes)
    const float* bias = (y == 0) ? bq : (y == 1) ? bk : bv;
    const int b   = m0 >> 12;
    const int s0b = m0 & 4095;
    unsigned short* vtr = &a_buf[0][0][0][0];  // alias: [64 d][72]

    #pragma unroll
    for (int nt = 0; nt < 2; nt++) {
        int col = ch * 32 + nt * 16 + l15;
        float bb = bias[col];
        int rloc = rs * 16 + quad * 4;   // local row 0..63
        #pragma unroll
        for (int r = 0; r < 4; r++) {
            float v = acc[nt][r] + bb;
            v = fmaxf(v, 0.f);
            size_t grow = (size_t)(m0 + rloc + r);
            if (y == 0) {
                unsigned short h = f2bf(v);
                unsigned short l = f2bf(v - bf2f(h));
                q_hi[grow * 64 + col] = h;
                q_lo[grow * 64 + col] = l;
            } else if (y == 1) {
                k_bf[grow * 64 + col] = f2bf(v);
            } else {
                vtr[col * 72 + rloc + r] = f2bf(v);  // transpose via LDS
            }
        }
    }
    if (y == 2) {
        __syncthreads();
        int row = tid >> 3;          // d 0..63
        int off = (tid & 7) * 8;     // s chunk
        s16x8 vv = *(const s16x8*)&vtr[row * 72 + off];
        *(s16x8*)(vt_g + (size_t)(b * 64 + row) * 4096 + s0b + off) = vv;
    }
}

// ---------------------------------------------------------------------------
// Kernel 3: fused attention, KV-split. grid (64 qtiles, 8 chunks, 4 batch) =
// 2048 blocks. Block = 64 q-rows, 4 waves, 8 KV tiles each. LDS 23.5 KB
// (pt halved: keys processed in two 32-key halves) -> 6 blocks/CU.
// Writes UNNORMALIZED partial O (bf16) and row-sum l (fp32).
// No online max: q,k >= 0 post-relu => exp safe in fp32.  (unchanged)
// ---------------------------------------------------------------------------
__global__ __launch_bounds__(256, 6) void attn_kernel(
    const unsigned short* __restrict__ q_hi, const unsigned short* __restrict__ q_lo,
    const unsigned short* __restrict__ k_bf, const unsigned short* __restrict__ vt_g,
    unsigned short* __restrict__ pOb, float* __restrict__ pL)
{
    __shared__ __align__(16) unsigned short kt[64][72];      // [key][dim]
    __shared__ __align__(16) unsigned short vt[64][72];      // [dim][key]  (V^T)
    __shared__ __align__(16) unsigned short pt[4][16][40];   // per-wave P [q][key half]

    const int tid  = threadIdx.x;
    const int lane = tid & 63;
    const int w    = tid >> 6;
    const int quad = lane >> 4;
    const int l15  = lane & 15;
    const int ck   = blockIdx.y;         // key chunk (512 keys)
    const int b    = blockIdx.z;
    const int q0   = blockIdx.x * 64;    // within batch

    const size_t qoff = ((size_t)b * 4096 + q0 + w * 16 + l15) * 64 + quad * 8;
    s16x8 qh0 = *(const s16x8*)(q_hi + qoff);
    s16x8 qh1 = *(const s16x8*)(q_hi + qoff + 32);
    s16x8 ql0 = *(const s16x8*)(q_lo + qoff);
    s16x8 ql1 = *(const s16x8*)(q_lo + qoff + 32);

    fx4 accO[4];
    #pragma unroll
    for (int nt = 0; nt < 4; nt++) accO[nt] = (fx4){0.f, 0.f, 0.f, 0.f};
    float lsum[4] = {0.f, 0.f, 0.f, 0.f};

    const unsigned short* kgb = k_bf + (size_t)b * 4096 * 64;  // [s][64]
    const unsigned short* vgb = vt_g + (size_t)b * 64 * 4096;  // [d][s]

    const int srow = tid >> 3;        // 0..31
    const int soff = (tid & 7) * 8;

    for (int it = ck * 8; it < ck * 8 + 8; it++) {
        const unsigned short* kg = kgb + (size_t)it * 4096;    // 64 keys x 64 dims
        #pragma unroll
        for (int i = 0; i < 2; i++) {
            int row = srow + i * 32;
            *(s16x8*)&kt[row][soff] = *(const s16x8*)(kg + (size_t)row * 64 + soff);
            *(s16x8*)&vt[row][soff] = *(const s16x8*)(vgb + (size_t)row * 4096 + it * 64 + soff);
        }
        __syncthreads();

        #pragma unroll
        for (int kh = 0; kh < 2; kh++) {
            #pragma unroll
            for (int nt2 = 0; nt2 < 2; nt2++) {
                int key = kh * 32 + nt2 * 16 + l15;
                s16x8 k0 = *(const s16x8*)&kt[key][quad * 8];
                s16x8 k1 = *(const s16x8*)&kt[key][32 + quad * 8];
                fx4 sc = (fx4){0.f, 0.f, 0.f, 0.f};
                sc = __builtin_amdgcn_mfma_f32_16x16x32_bf16(qh0, k0, sc, 0, 0, 0);
                sc = __builtin_amdgcn_mfma_f32_16x16x32_bf16(ql0, k0, sc, 0, 0, 0);
                sc = __builtin_amdgcn_mfma_f32_16x16x32_bf16(qh1, k1, sc, 0, 0, 0);
                sc = __builtin_amdgcn_mfma_f32_16x16x32_bf16(ql1, k1, sc, 0, 0, 0);
                #pragma unroll
                for (int r = 0; r < 4; r++) {
                    float p = __builtin_amdgcn_exp2f(sc[r] * LOG2E);
                    unsigned short pb = f2bf(p);
                    lsum[r] += bf2f(pb);   // denominator matches rounded numerator
                    pt[w][quad * 4 + r][nt2 * 16 + l15] = pb;
                }
            }
            s16x8 pa = *(const s16x8*)&pt[w][l15][quad * 8];
            #pragma unroll
            for (int nt = 0; nt < 4; nt++) {
                s16x8 vf = *(const s16x8*)&vt[nt * 16 + l15][kh * 32 + quad * 8];
                accO[nt] = __builtin_amdgcn_mfma_f32_16x16x32_bf16(pa, vf, accO[nt], 0, 0, 0);
            }
        }
        __syncthreads();
    }

    #pragma unroll
    for (int r = 0; r < 4; r++) {
        float v = lsum[r];
        #pragma unroll
        for (int o = 1; o < 16; o <<= 1) v += __shfl_xor(v, o);
        lsum[r] = v;
    }
    #pragma unroll
    for (int r = 0; r < 4; r++) {
        int qrow = q0 + w * 16 + quad * 4 + r;
        size_t grow = (size_t)b * 4096 + qrow;
        #pragma unroll
        for (int nt = 0; nt < 4; nt++)
            pOb[((size_t)ck * 16384 + grow) * 64 + nt * 16 + l15] = f2bf(accO[nt][r]);
        if (l15 == 0)
            pL[(size_t)ck * 16384 + grow] = lsum[r];
    }
}

// ---------------------------------------------------------------------------
// Kernel 4: combine partials: out = (sum_c pOb) * mask / (sum_c pL)  (unchanged)
// ---------------------------------------------------------------------------
__global__ __launch_bounds__(256) void combine_kernel(
    const unsigned short* __restrict__ pOb, const float* __restrict__ pL,
    const float* __restrict__ mask, float* __restrict__ out)
{
    int idx = blockIdx.x * 256 + threadIdx.x;   // 262144 = (b*4096+s)*16 + dgrp
    int q  = idx >> 4;
    int dg = idx & 15;
    fx4 s = (fx4){0.f, 0.f, 0.f, 0.f};
    float l = 0.f;
    #pragma unroll
    for (int c = 0; c < 8; c++) {
        u16x4 h = *(const u16x4*)(pOb + ((size_t)c * 16384 + q) * 64 + dg * 4);
        s.x += bf2f(h.x);
        s.y += bf2f(h.y);
        s.z += bf2f(h.z);
        s.w += bf2f(h.w);
        l += pL[(size_t)c * 16384 + q];
    }
    float scale = mask[q] / l;
    *(fx4*)(out + (size_t)q * 64 + dg * 4) = s * scale;
}

// ---------------------------------------------------------------------------
extern "C" void kernel_launch(void* const* d_in, const int* in_sizes, int n_in,
                              void* d_out, int out_size, void* d_ws, size_t ws_size,
                              hipStream_t stream)
{
    const float* X    = (const float*)d_in[0];
    const float* mask = (const float*)d_in[1];
    const float* Wq   = (const float*)d_in[2];
    const float* bq   = (const float*)d_in[3];
    const float* Wk   = (const float*)d_in[4];
    const float* bk   = (const float*)d_in[5];
    const float* Wv   = (const float*)d_in[6];
    const float* bv   = (const float*)d_in[7];
    float* out = (float*)d_out;

    char* ws = (char*)d_ws;
    unsigned short* q_hi  = (unsigned short*)(ws);                       // 2 MB
    unsigned short* q_lo  = (unsigned short*)(ws + (size_t)(2u << 20));  // 2 MB
    unsigned short* k_bf  = (unsigned short*)(ws + (size_t)(4u << 20));  // 2 MB
    unsigned short* vt_g  = (unsigned short*)(ws + (size_t)(6u << 20));  // 2 MB  [b][d][s]
    unsigned short* wt_hi = (unsigned short*)(ws + (size_t)(8u << 20));  // 384 KB
    unsigned short* wt_lo = (unsigned short*)(ws + (size_t)(8u << 20) + 393216);
    unsigned short* pOb   = (unsigned short*)(ws + (size_t)(9u << 20));  // 16 MB [8][16384][64] bf16
    float*          pL    = (float*)(ws + (size_t)(25u << 20));          // 512 KB [8][16384]

    hipLaunchKernelGGL(prep_w_kernel, dim3(3, 16), dim3(256), 0, stream,
                       Wq, Wk, Wv, wt_hi, wt_lo);
    hipLaunchKernelGGL(proj_kernel, dim3(768), dim3(512), 0, stream,
                       X, wt_hi, wt_lo, bq, bk, bv, q_hi, q_lo, k_bf, vt_g);
    hipLaunchKernelGGL(attn_kernel, dim3(64, 8, 4), dim3(256), 0, stream,
                       q_hi, q_lo, k_bf, vt_g, pOb, pL);
    hipLaunchKernelGGL(combine_kernel, dim3(1024), dim3(256), 0, stream,
                       pOb, pL, mask, out);
}

// Round 2
// 185.800 us; speedup vs baseline: 1.2388x; 1.2388x over previous
//
#include <hip/hip_runtime.h>

// B=4, S=4096, D_IN=1024, D_QK=D_V=64
// out = softmax(relu(XWq+bq) @ relu(XWk+bk)^T) @ relu(XWv+bv) * mask

typedef short s16x8 __attribute__((ext_vector_type(8)));   // 8 bf16 (4 VGPRs) MFMA frag
typedef float fx4   __attribute__((ext_vector_type(4)));   // MFMA accum frag
typedef unsigned short u16x4 __attribute__((ext_vector_type(4)));

#define LOG2E 1.4426950408889634f

__device__ __forceinline__ unsigned short f2bf(float x) {   // fp32 -> bf16 RTN
    unsigned int u = __float_as_uint(x);
    u += 0x7FFFu + ((u >> 16) & 1u);
    return (unsigned short)(u >> 16);
}
__device__ __forceinline__ float bf2f(unsigned short b) {
    return __uint_as_float(((unsigned int)b) << 16);
}

// ---------------------------------------------------------------------------
// Kernel 1: split W{q,k,v} [1024][64] fp32 into W^T hi/lo bf16 [3][64][1024].
// LDS tile-transpose; coalesced reads, contiguous 32 B runs along k going out.
// grid (3 y, 16 k-tiles) x 256.  (unchanged)
// ---------------------------------------------------------------------------
__global__ __launch_bounds__(256) void prep_w_kernel(
    const float* __restrict__ Wq, const float* __restrict__ Wk, const float* __restrict__ Wv,
    unsigned short* __restrict__ wt_hi, unsigned short* __restrict__ wt_lo)
{
    __shared__ __align__(16) unsigned short sh[64][72];   // [c][k_local]
    __shared__ __align__(16) unsigned short sl[64][72];

    const int y  = blockIdx.x;
    const int kt = blockIdx.y;
    const float* W = (y == 0) ? Wq : (y == 1) ? Wk : Wv;
    const int t  = threadIdx.x;

    const int kl = t >> 2;
    const int c0 = (t & 3) * 16;
    const float* src = W + (size_t)(kt * 64 + kl) * 64 + c0;
    #pragma unroll
    for (int j = 0; j < 4; j++) {
        fx4 v = *(const fx4*)(src + j * 4);
        #pragma unroll
        for (int i = 0; i < 4; i++) {
            float x = v[i];
            unsigned short h = f2bf(x);
            unsigned short l = f2bf(x - bf2f(h));
            sh[c0 + j * 4 + i][kl] = h;
            sl[c0 + j * 4 + i][kl] = l;
        }
    }
    __syncthreads();

    const int c  = t >> 2;
    const int k0 = (t & 3) * 16;
    size_t o = (size_t)(y * 64 + c) * 1024 + kt * 64 + k0;
    *(s16x8*)(wt_hi + o)     = *(const s16x8*)&sh[c][k0];
    *(s16x8*)(wt_hi + o + 8) = *(const s16x8*)&sh[c][k0 + 8];
    *(s16x8*)(wt_lo + o)     = *(const s16x8*)&sl[c][k0];
    *(s16x8*)(wt_lo + o + 8) = *(const s16x8*)&sl[c][k0 + 8];
}

// ---------------------------------------------------------------------------
// Kernel 2 (v4): fused q/k/v projection. Grid 256 (one 64-row m-tile per
// block, 1 block/CU), block 768 = 12 waves arranged 2 row-groups x 6
// col-groups (3 y-matrices x 2 col-halves). X is staged to LDS ONCE per
// m-tile and feeds all three projections (v2 staged it 3x in 3 blocks).
// Wave tile 32x32: 8 LDS A-frag reads per 24 MFMAs (v2: 12 reads / 12
// MFMAs). W frags come straight from global (L1/L2-resident, 768 KB total)
// via explicit ping-pong register prefetch issued one kc ahead -- the v3
// regression was this path WITHOUT prefetch registers (VGPR=36 under
// launch_bounds(512,6) serialized 8 L2 latencies per kc). launch_bounds
// (768,3) caps VGPR at 170 (~150 used), full unroll makes all prefetch
// buffer indices static and folds offsets into load immediates. One
// barrier per kc (true LDS dbuf). Identical per-output op order => bit-
// identical results.
// ---------------------------------------------------------------------------
__global__ __launch_bounds__(768, 3) void proj_kernel(
    const float* __restrict__ X,
    const unsigned short* __restrict__ wt_hi, const unsigned short* __restrict__ wt_lo,
    const float* __restrict__ bq, const float* __restrict__ bk, const float* __restrict__ bv,
    unsigned short* __restrict__ q_hi, unsigned short* __restrict__ q_lo,
    unsigned short* __restrict__ k_bf, unsigned short* __restrict__ vt_g)
{
    // [dbuf][hi/lo][row][col], +8 pad (row stride 144B: 2-way bank alias, free)
    __shared__ __align__(16) unsigned short a_buf[2][2][64][72];

    const int tid  = threadIdx.x;
    const int lane = tid & 63;
    const int w    = tid >> 6;      // 0..11
    const int quad = lane >> 4;
    const int l15  = lane & 15;
    const int rowg = w & 1;         // 32-row group
    const int colg = w >> 1;        // 0..5 across {q,k,v} x {lo,hi 32 cols}
    const int y    = colg >> 1;     // 0=q 1=k 2=v
    const int ch   = colg & 1;      // 32-col half within y

    const int m0 = blockIdx.x * 64;

    fx4 acc[2][2];                  // [sub(16 rows)][nt(16 cols)]
    #pragma unroll
    for (int i = 0; i < 2; i++)
        #pragma unroll
        for (int j = 0; j < 2; j++) acc[i][j] = (fx4){0.f, 0.f, 0.f, 0.f};

    // X staging: threads 0..511 handle 8 floats each (rows xrow, xrow+32)
    const int xrow = tid >> 4;        // 0..31 (valid for tid<512)
    const int xoff = (tid & 15) * 4;
    const float* xb0 = X + (size_t)(m0 + xrow) * 1024 + xoff;
    const float* xb1 = X + (size_t)(m0 + xrow + 32) * 1024 + xoff;

    // per-lane W-frag bases: row = y*64 + ch*32 + nt*16 + l15, col base quad*8
    const size_t wb = (size_t)(y * 64 + ch * 32 + l15) * 1024 + quad * 8;
    const unsigned short* wph[2] = { wt_hi + wb, wt_hi + wb + 16 * 1024 };
    const unsigned short* wpl[2] = { wt_lo + wb, wt_lo + wb + 16 * 1024 };

    // convert one X chunk (2 fx4/thread) to hi/lo bf16 and stage into buf d
    auto cvt_store = [&](int d, fx4 va, fx4 vb) {
        #pragma unroll
        for (int i = 0; i < 2; i++) {
            fx4 xv = i ? vb : va;
            unsigned short h0 = f2bf(xv.x), h1 = f2bf(xv.y), h2 = f2bf(xv.z), h3 = f2bf(xv.w);
            unsigned short l0 = f2bf(xv.x - bf2f(h0)), l1 = f2bf(xv.y - bf2f(h1));
            unsigned short l2 = f2bf(xv.z - bf2f(h2)), l3 = f2bf(xv.w - bf2f(h3));
            *(u16x4*)&a_buf[d][0][xrow + i * 32][xoff] = (u16x4){h0, h1, h2, h3};
            *(u16x4*)&a_buf[d][1][xrow + i * 32][xoff] = (u16x4){l0, l1, l2, l3};
        }
    };

    // prologue: chunk 0 -> buf0; X reg pipeline holds chunks 1,2;
    // B regs ping-pong buf0 <- kc0
    fx4 xr[2][2];
    if (tid < 512) {
        cvt_store(0, *(const fx4*)xb0, *(const fx4*)xb1);
        xr[1][0] = *(const fx4*)(xb0 + 64);
        xr[1][1] = *(const fx4*)(xb1 + 64);
        xr[0][0] = *(const fx4*)(xb0 + 128);
        xr[0][1] = *(const fx4*)(xb1 + 128);
    }
    s16x8 Bh[2][2][2], Bl[2][2][2];   // [pingpong][nt][ks]
    #pragma unroll
    for (int nt = 0; nt < 2; nt++)
        #pragma unroll
        for (int ks = 0; ks < 2; ks++) {
            Bh[0][nt][ks] = *(const s16x8*)(wph[nt] + ks * 32);
            Bl[0][nt][ks] = *(const s16x8*)(wpl[nt] + ks * 32);
        }
    __syncthreads();

    #pragma unroll
    for (int kc = 0; kc < 16; kc++) {
        const int cur = kc & 1;
        // B prefetch for kc+1 (consumed after next barrier: ~full-kc latency window)
        if (kc < 15) {
            #pragma unroll
            for (int nt = 0; nt < 2; nt++)
                #pragma unroll
                for (int ks = 0; ks < 2; ks++) {
                    Bh[cur ^ 1][nt][ks] = *(const s16x8*)(wph[nt] + (kc + 1) * 64 + ks * 32);
                    Bl[cur ^ 1][nt][ks] = *(const s16x8*)(wpl[nt] + (kc + 1) * 64 + ks * 32);
                }
        }
        if (tid < 512) {
            // stage chunk kc+1 into other buffer (its prior readers finished
            // before last iteration's trailing barrier)
            if (kc < 15) cvt_store(cur ^ 1, xr[(kc + 1) & 1][0], xr[(kc + 1) & 1][1]);
            // refill X reg slot with chunk kc+3 (consumed at iter kc+2)
            if (kc < 13) {
                xr[(kc + 1) & 1][0] = *(const fx4*)(xb0 + (kc + 3) * 64);
                xr[(kc + 1) & 1][1] = *(const fx4*)(xb1 + (kc + 3) * 64);
            }
        }
        // A frags from LDS (32 rows: sub=0,1)
        s16x8 ah[2][2], al[2][2];
        #pragma unroll
        for (int sub = 0; sub < 2; sub++)
            #pragma unroll
            for (int ks = 0; ks < 2; ks++) {
                const int r = rowg * 32 + sub * 16 + l15;
                ah[sub][ks] = *(const s16x8*)&a_buf[cur][0][r][ks * 32 + quad * 8];
                al[sub][ks] = *(const s16x8*)&a_buf[cur][1][r][ks * 32 + quad * 8];
            }
        #pragma unroll
        for (int sub = 0; sub < 2; sub++)
            #pragma unroll
            for (int nt = 0; nt < 2; nt++)
                #pragma unroll
                for (int ks = 0; ks < 2; ks++) {
                    acc[sub][nt] = __builtin_amdgcn_mfma_f32_16x16x32_bf16(ah[sub][ks], Bh[cur][nt][ks], acc[sub][nt], 0, 0, 0);
                    acc[sub][nt] = __builtin_amdgcn_mfma_f32_16x16x32_bf16(ah[sub][ks], Bl[cur][nt][ks], acc[sub][nt], 0, 0, 0);
                    acc[sub][nt] = __builtin_amdgcn_mfma_f32_16x16x32_bf16(al[sub][ks], Bh[cur][nt][ks], acc[sub][nt], 0, 0, 0);
                }
        __syncthreads();   // staged buffer ready; this iter's LDS reads drained
    }

    // epilogue: bias + relu; q -> hi/lo, k -> bf16, v -> LDS transpose
    const float* bias = (y == 0) ? bq : (y == 1) ? bk : bv;
    const int b   = m0 >> 12;
    const int s0b = m0 & 4095;
    unsigned short* vtr = &a_buf[0][0][0][0];  // alias: [64 d][72]

    #pragma unroll
    for (int sub = 0; sub < 2; sub++)
        #pragma unroll
        for (int nt = 0; nt < 2; nt++) {
            const int col = ch * 32 + nt * 16 + l15;
            const float bb = bias[col];
            const int rloc = rowg * 32 + sub * 16 + quad * 4;
            #pragma unroll
            for (int r = 0; r < 4; r++) {
                float v = fmaxf(acc[sub][nt][r] + bb, 0.f);
                size_t grow = (size_t)(m0 + rloc + r);
                if (y == 0) {
                    unsigned short h = f2bf(v);
                    unsigned short l = f2bf(v - bf2f(h));
                    q_hi[grow * 64 + col] = h;
                    q_lo[grow * 64 + col] = l;
                } else if (y == 1) {
                    k_bf[grow * 64 + col] = f2bf(v);
                } else {
                    vtr[col * 72 + rloc + r] = f2bf(v);  // transpose via LDS
                }
            }
        }
    __syncthreads();   // v-waves' vtr writes visible to storing threads
    if (tid < 512) {
        int row = tid >> 3;          // d 0..63
        int off = (tid & 7) * 8;     // s chunk
        s16x8 vv = *(const s16x8*)&vtr[row * 72 + off];
        *(s16x8*)(vt_g + (size_t)(b * 64 + row) * 4096 + s0b + off) = vv;
    }
}

// ---------------------------------------------------------------------------
// Kernel 3: fused attention, KV-split. grid (64 qtiles, 8 chunks, 4 batch) =
// 2048 blocks. Block = 64 q-rows, 4 waves, 8 KV tiles each. LDS 23.5 KB
// (pt halved: keys processed in two 32-key halves) -> 6 blocks/CU.
// Writes UNNORMALIZED partial O (bf16) and row-sum l (fp32).
// No online max: q,k >= 0 post-relu => exp safe in fp32.  (unchanged)
// ---------------------------------------------------------------------------
__global__ __launch_bounds__(256, 6) void attn_kernel(
    const unsigned short* __restrict__ q_hi, const unsigned short* __restrict__ q_lo,
    const unsigned short* __restrict__ k_bf, const unsigned short* __restrict__ vt_g,
    unsigned short* __restrict__ pOb, float* __restrict__ pL)
{
    __shared__ __align__(16) unsigned short kt[64][72];      // [key][dim]
    __shared__ __align__(16) unsigned short vt[64][72];      // [dim][key]  (V^T)
    __shared__ __align__(16) unsigned short pt[4][16][40];   // per-wave P [q][key half]

    const int tid  = threadIdx.x;
    const int lane = tid & 63;
    const int w    = tid >> 6;
    const int quad = lane >> 4;
    const int l15  = lane & 15;
    const int ck   = blockIdx.y;         // key chunk (512 keys)
    const int b    = blockIdx.z;
    const int q0   = blockIdx.x * 64;    // within batch

    const size_t qoff = ((size_t)b * 4096 + q0 + w * 16 + l15) * 64 + quad * 8;
    s16x8 qh0 = *(const s16x8*)(q_hi + qoff);
    s16x8 qh1 = *(const s16x8*)(q_hi + qoff + 32);
    s16x8 ql0 = *(const s16x8*)(q_lo + qoff);
    s16x8 ql1 = *(const s16x8*)(q_lo + qoff + 32);

    fx4 accO[4];
    #pragma unroll
    for (int nt = 0; nt < 4; nt++) accO[nt] = (fx4){0.f, 0.f, 0.f, 0.f};
    float lsum[4] = {0.f, 0.f, 0.f, 0.f};

    const unsigned short* kgb = k_bf + (size_t)b * 4096 * 64;  // [s][64]
    const unsigned short* vgb = vt_g + (size_t)b * 64 * 4096;  // [d][s]

    const int srow = tid >> 3;        // 0..31
    const int soff = (tid & 7) * 8;

    for (int it = ck * 8; it < ck * 8 + 8; it++) {
        const unsigned short* kg = kgb + (size_t)it * 4096;    // 64 keys x 64 dims
        #pragma unroll
        for (int i = 0; i < 2; i++) {
            int row = srow + i * 32;
            *(s16x8*)&kt[row][soff] = *(const s16x8*)(kg + (size_t)row * 64 + soff);
            *(s16x8*)&vt[row][soff] = *(const s16x8*)(vgb + (size_t)row * 4096 + it * 64 + soff);
        }
        __syncthreads();

        #pragma unroll
        for (int kh = 0; kh < 2; kh++) {
            #pragma unroll
            for (int nt2 = 0; nt2 < 2; nt2++) {
                int key = kh * 32 + nt2 * 16 + l15;
                s16x8 k0 = *(const s16x8*)&kt[key][quad * 8];
                s16x8 k1 = *(const s16x8*)&kt[key][32 + quad * 8];
                fx4 sc = (fx4){0.f, 0.f, 0.f, 0.f};
                sc = __builtin_amdgcn_mfma_f32_16x16x32_bf16(qh0, k0, sc, 0, 0, 0);
                sc = __builtin_amdgcn_mfma_f32_16x16x32_bf16(ql0, k0, sc, 0, 0, 0);
                sc = __builtin_amdgcn_mfma_f32_16x16x32_bf16(qh1, k1, sc, 0, 0, 0);
                sc = __builtin_amdgcn_mfma_f32_16x16x32_bf16(ql1, k1, sc, 0, 0, 0);
                #pragma unroll
                for (int r = 0; r < 4; r++) {
                    float p = __builtin_amdgcn_exp2f(sc[r] * LOG2E);
                    unsigned short pb = f2bf(p);
                    lsum[r] += bf2f(pb);   // denominator matches rounded numerator
                    pt[w][quad * 4 + r][nt2 * 16 + l15] = pb;
                }
            }
            s16x8 pa = *(const s16x8*)&pt[w][l15][quad * 8];
            #pragma unroll
            for (int nt = 0; nt < 4; nt++) {
                s16x8 vf = *(const s16x8*)&vt[nt * 16 + l15][kh * 32 + quad * 8];
                accO[nt] = __builtin_amdgcn_mfma_f32_16x16x32_bf16(pa, vf, accO[nt], 0, 0, 0);
            }
        }
        __syncthreads();
    }

    #pragma unroll
    for (int r = 0; r < 4; r++) {
        float v = lsum[r];
        #pragma unroll
        for (int o = 1; o < 16; o <<= 1) v += __shfl_xor(v, o);
        lsum[r] = v;
    }
    #pragma unroll
    for (int r = 0; r < 4; r++) {
        int qrow = q0 + w * 16 + quad * 4 + r;
        size_t grow = (size_t)b * 4096 + qrow;
        #pragma unroll
        for (int nt = 0; nt < 4; nt++)
            pOb[((size_t)ck * 16384 + grow) * 64 + nt * 16 + l15] = f2bf(accO[nt][r]);
        if (l15 == 0)
            pL[(size_t)ck * 16384 + grow] = lsum[r];
    }
}

// ---------------------------------------------------------------------------
// Kernel 4: combine partials: out = (sum_c pOb) * mask / (sum_c pL)  (unchanged)
// ---------------------------------------------------------------------------
__global__ __launch_bounds__(256) void combine_kernel(
    const unsigned short* __restrict__ pOb, const float* __restrict__ pL,
    const float* __restrict__ mask, float* __restrict__ out)
{
    int idx = blockIdx.x * 256 + threadIdx.x;   // 262144 = (b*4096+s)*16 + dgrp
    int q  = idx >> 4;
    int dg = idx & 15;
    fx4 s = (fx4){0.f, 0.f, 0.f, 0.f};
    float l = 0.f;
    #pragma unroll
    for (int c = 0; c < 8; c++) {
        u16x4 h = *(const u16x4*)(pOb + ((size_t)c * 16384 + q) * 64 + dg * 4);
        s.x += bf2f(h.x);
        s.y += bf2f(h.y);
        s.z += bf2f(h.z);
        s.w += bf2f(h.w);
        l += pL[(size_t)c * 16384 + q];
    }
    float scale = mask[q] / l;
    *(fx4*)(out + (size_t)q * 64 + dg * 4) = s * scale;
}

// ---------------------------------------------------------------------------
extern "C" void kernel_launch(void* const* d_in, const int* in_sizes, int n_in,
                              void* d_out, int out_size, void* d_ws, size_t ws_size,
                              hipStream_t stream)
{
    const float* X    = (const float*)d_in[0];
    const float* mask = (const float*)d_in[1];
    const float* Wq   = (const float*)d_in[2];
    const float* bq   = (const float*)d_in[3];
    const float* Wk   = (const float*)d_in[4];
    const float* bk   = (const float*)d_in[5];
    const float* Wv   = (const float*)d_in[6];
    const float* bv   = (const float*)d_in[7];
    float* out = (float*)d_out;

    char* ws = (char*)d_ws;
    unsigned short* q_hi  = (unsigned short*)(ws);                       // 2 MB
    unsigned short* q_lo  = (unsigned short*)(ws + (size_t)(2u << 20));  // 2 MB
    unsigned short* k_bf  = (unsigned short*)(ws + (size_t)(4u << 20));  // 2 MB
    unsigned short* vt_g  = (unsigned short*)(ws + (size_t)(6u << 20));  // 2 MB  [b][d][s]
    unsigned short* wt_hi = (unsigned short*)(ws + (size_t)(8u << 20));  // 384 KB
    unsigned short* wt_lo = (unsigned short*)(ws + (size_t)(8u << 20) + 393216);
    unsigned short* pOb   = (unsigned short*)(ws + (size_t)(9u << 20));  // 16 MB [8][16384][64] bf16
    float*          pL    = (float*)(ws + (size_t)(25u << 20));          // 512 KB [8][16384]

    hipLaunchKernelGGL(prep_w_kernel, dim3(3, 16), dim3(256), 0, stream,
                       Wq, Wk, Wv, wt_hi, wt_lo);
    hipLaunchKernelGGL(proj_kernel, dim3(256), dim3(768), 0, stream,
                       X, wt_hi, wt_lo, bq, bk, bv, q_hi, q_lo, k_bf, vt_g);
    hipLaunchKernelGGL(attn_kernel, dim3(64, 8, 4), dim3(256), 0, stream,
                       q_hi, q_lo, k_bf, vt_g, pOb, pL);
    hipLaunchKernelGGL(combine_kernel, dim3(1024), dim3(256), 0, stream,
                       pOb, pL, mask, out);
}

// Round 4
// 174.076 us; speedup vs baseline: 1.3222x; 1.0674x over previous
//
#include <hip/hip_runtime.h>

// B=4, S=4096, D_IN=1024, D_QK=D_V=64
// out = softmax(relu(XWq+bq) @ relu(XWk+bk)^T) @ relu(XWv+bv) * mask

typedef short s16x8 __attribute__((ext_vector_type(8)));   // 8 bf16 (4 VGPRs) MFMA frag
typedef float fx4   __attribute__((ext_vector_type(4)));   // MFMA accum frag
typedef unsigned short u16x4 __attribute__((ext_vector_type(4)));

#define LOG2E 1.4426950408889634f

__device__ __forceinline__ unsigned short f2bf(float x) {   // fp32 -> bf16 RTN
    unsigned int u = __float_as_uint(x);
    u += 0x7FFFu + ((u >> 16) & 1u);
    return (unsigned short)(u >> 16);
}
__device__ __forceinline__ float bf2f(unsigned short b) {
    return __uint_as_float(((unsigned int)b) << 16);
}

// ---------------------------------------------------------------------------
// Kernel 1: split W{q,k,v} [1024][64] fp32 into W^T hi/lo bf16 [3][64][1024].
// LDS tile-transpose; coalesced reads, contiguous 32 B runs along k going out.
// grid (3 y, 16 k-tiles) x 256.  (unchanged)
// ---------------------------------------------------------------------------
__global__ __launch_bounds__(256) void prep_w_kernel(
    const float* __restrict__ Wq, const float* __restrict__ Wk, const float* __restrict__ Wv,
    unsigned short* __restrict__ wt_hi, unsigned short* __restrict__ wt_lo)
{
    __shared__ __align__(16) unsigned short sh[64][72];   // [c][k_local]
    __shared__ __align__(16) unsigned short sl[64][72];

    const int y  = blockIdx.x;
    const int kt = blockIdx.y;
    const float* W = (y == 0) ? Wq : (y == 1) ? Wk : Wv;
    const int t  = threadIdx.x;

    const int kl = t >> 2;
    const int c0 = (t & 3) * 16;
    const float* src = W + (size_t)(kt * 64 + kl) * 64 + c0;
    #pragma unroll
    for (int j = 0; j < 4; j++) {
        fx4 v = *(const fx4*)(src + j * 4);
        #pragma unroll
        for (int i = 0; i < 4; i++) {
            float x = v[i];
            unsigned short h = f2bf(x);
            unsigned short l = f2bf(x - bf2f(h));
            sh[c0 + j * 4 + i][kl] = h;
            sl[c0 + j * 4 + i][kl] = l;
        }
    }
    __syncthreads();

    const int c  = t >> 2;
    const int k0 = (t & 3) * 16;
    size_t o = (size_t)(y * 64 + c) * 1024 + kt * 64 + k0;
    *(s16x8*)(wt_hi + o)     = *(const s16x8*)&sh[c][k0];
    *(s16x8*)(wt_hi + o + 8) = *(const s16x8*)&sh[c][k0 + 8];
    *(s16x8*)(wt_lo + o)     = *(const s16x8*)&sl[c][k0];
    *(s16x8*)(wt_lo + o + 8) = *(const s16x8*)&sl[c][k0 + 8];
}

// ---------------------------------------------------------------------------
// Kernel 2: projection -- proven v2 structure (47 us). B stays in LDS
// (v3/v4 showed the compiler won't keep a global->reg ping-pong live across
// __syncthreads). 1D grid 768, XCD-swizzled (3 y-blocks of one X m-tile
// share an XCD => X fetched once per XCD). Block 512 (8 waves = 4 row-
// subtiles x 2 col-halves), M-tile 64. X prefetch depth 4, W depth 2.
// Compensated bf16 MFMA (hh+hl+lh).
// ---------------------------------------------------------------------------
__global__ __launch_bounds__(512, 4) void proj_kernel(
    const float* __restrict__ X,
    const unsigned short* __restrict__ wt_hi, const unsigned short* __restrict__ wt_lo,
    const float* __restrict__ bq, const float* __restrict__ bk, const float* __restrict__ bv,
    unsigned short* __restrict__ q_hi, unsigned short* __restrict__ q_lo,
    unsigned short* __restrict__ k_bf, unsigned short* __restrict__ vt_g)
{
    __shared__ __align__(16) unsigned short a_buf[2][64][72];  // X tile hi/lo, +8 pad
    __shared__ __align__(16) unsigned short b_hi[64][72];      // W^T tile hi [col][k]
    __shared__ __align__(16) unsigned short b_lo[64][72];

    const int tid  = threadIdx.x;
    const int lane = tid & 63;
    const int w    = tid >> 6;      // 0..7
    const int quad = lane >> 4;
    const int l15  = lane & 15;
    const int rs   = w & 3;         // row-subtile (16 rows)
    const int ch   = w >> 2;        // col half (32 cols)

    // XCD swizzle decode: f = (m & 7) + 8*(y + 3*(m >> 3))
    const int f   = blockIdx.x;
    const int xcd = f & 7;
    const int jj  = f >> 3;
    const int y   = jj % 3;         // 0=q 1=k 2=v
    const int m0  = ((jj / 3) * 8 + xcd) * 64;

    fx4 acc[2];
    acc[0] = (fx4){0.f, 0.f, 0.f, 0.f};
    acc[1] = (fx4){0.f, 0.f, 0.f, 0.f};

    const int xrow = tid >> 4;        // 0..31
    const int xoff = (tid & 15) * 4;
    const int wrow = tid >> 3;        // 0..63
    const int woff = (tid & 7) * 8;

    const float* xb0 = X + (size_t)(m0 + xrow) * 1024 + xoff;
    const float* xb1 = X + (size_t)(m0 + xrow + 32) * 1024 + xoff;
    const size_t wb  = (size_t)(y * 64 + wrow) * 1024 + woff;

    // rolling prefetch buffers: X depth 4, W depth 2
    fx4   xr[4][2];
    s16x8 wrh[2], wrl[2];
    #pragma unroll
    for (int d = 0; d < 4; d++) {
        xr[d][0] = *(const fx4*)(xb0 + d * 64);
        xr[d][1] = *(const fx4*)(xb1 + d * 64);
    }
    #pragma unroll
    for (int d = 0; d < 2; d++) {
        wrh[d] = *(const s16x8*)(wt_hi + wb + d * 64);
        wrl[d] = *(const s16x8*)(wt_lo + wb + d * 64);
    }

    #pragma unroll 4
    for (int kc = 0; kc < 16; kc++) {
        if (kc) __syncthreads();   // prev iter's LDS readers done
        #pragma unroll
        for (int i = 0; i < 2; i++) {
            fx4 xv = xr[kc & 3][i];
            unsigned short h0 = f2bf(xv.x), h1 = f2bf(xv.y), h2 = f2bf(xv.z), h3 = f2bf(xv.w);
            unsigned short l0 = f2bf(xv.x - bf2f(h0)), l1 = f2bf(xv.y - bf2f(h1));
            unsigned short l2 = f2bf(xv.z - bf2f(h2)), l3 = f2bf(xv.w - bf2f(h3));
            *(u16x4*)&a_buf[0][xrow + i * 32][xoff] = (u16x4){h0, h1, h2, h3};
            *(u16x4*)&a_buf[1][xrow + i * 32][xoff] = (u16x4){l0, l1, l2, l3};
        }
        *(s16x8*)&b_hi[wrow][woff] = wrh[kc & 1];
        *(s16x8*)&b_lo[wrow][woff] = wrl[kc & 1];
        __syncthreads();

        // refill pipeline (latency hidden behind this + next 3 iters' MFMAs)
        if (kc < 12) {
            xr[kc & 3][0] = *(const fx4*)(xb0 + (kc + 4) * 64);
            xr[kc & 3][1] = *(const fx4*)(xb1 + (kc + 4) * 64);
        }
        if (kc < 14) {
            wrh[kc & 1] = *(const s16x8*)(wt_hi + wb + (kc + 2) * 64);
            wrl[kc & 1] = *(const s16x8*)(wt_lo + wb + (kc + 2) * 64);
        }

        s16x8 ah[2], al[2];
        #pragma unroll
        for (int ks = 0; ks < 2; ks++) {
            int r = rs * 16 + l15;
            ah[ks] = *(const s16x8*)&a_buf[0][r][ks * 32 + quad * 8];
            al[ks] = *(const s16x8*)&a_buf[1][r][ks * 32 + quad * 8];
        }
        #pragma unroll
        for (int nt = 0; nt < 2; nt++) {
            #pragma unroll
            for (int ks = 0; ks < 2; ks++) {
                s16x8 bh = *(const s16x8*)&b_hi[ch * 32 + nt * 16 + l15][ks * 32 + quad * 8];
                s16x8 bl = *(const s16x8*)&b_lo[ch * 32 + nt * 16 + l15][ks * 32 + quad * 8];
                acc[nt] = __builtin_amdgcn_mfma_f32_16x16x32_bf16(ah[ks], bh, acc[nt], 0, 0, 0);
                acc[nt] = __builtin_amdgcn_mfma_f32_16x16x32_bf16(ah[ks], bl, acc[nt], 0, 0, 0);
                acc[nt] = __builtin_amdgcn_mfma_f32_16x16x32_bf16(al[ks], bh, acc[nt], 0, 0, 0);
            }
        }
    }
    __syncthreads();   // all MFMA LDS reads done before vtr alias writes

    // epilogue: bias + relu, write per-matrix
    const float* bias = (y == 0) ? bq : (y == 1) ? bk : bv;
    const int b   = m0 >> 12;
    const int s0b = m0 & 4095;
    unsigned short* vtr = &a_buf[0][0][0];  // alias: [64 d][72]

    #pragma unroll
    for (int nt = 0; nt < 2; nt++) {
        int col = ch * 32 + nt * 16 + l15;
        float bb = bias[col];
        int rloc = rs * 16 + quad * 4;   // local row 0..63
        #pragma unroll
        for (int r = 0; r < 4; r++) {
            float v = acc[nt][r] + bb;
            v = fmaxf(v, 0.f);
            size_t grow = (size_t)(m0 + rloc + r);
            if (y == 0) {
                unsigned short h = f2bf(v);
                unsigned short l = f2bf(v - bf2f(h));
                q_hi[grow * 64 + col] = h;
                q_lo[grow * 64 + col] = l;
            } else if (y == 1) {
                k_bf[grow * 64 + col] = f2bf(v);
            } else {
                vtr[col * 72 + rloc + r] = f2bf(v);  // transpose via LDS
            }
        }
    }
    if (y == 2) {
        __syncthreads();
        int row = tid >> 3;          // d 0..63
        int off = (tid & 7) * 8;     // s chunk
        s16x8 vv = *(const s16x8*)&vtr[row * 72 + off];
        *(s16x8*)(vt_g + (size_t)(b * 64 + row) * 4096 + s0b + off) = vv;
    }
}

// ---------------------------------------------------------------------------
// Kernel 3 (v5): fused attention, KV-split. Changes vs v2-attn:
//  (1) 128 q-rows per block (8 waves, grid 32 x 8 x 4 = 1024): each staged
//      64-key K/V tile now feeds 2x the compute -> K/V global reads and LDS
//      staging per q-row halved. Per-wave math is UNCHANGED (wave owns 16 q
//      rows, wave-private pt slice) => bit-identical output.
//  (2) T14 async-STAGE split: next K/V tile is prefetched into 8 registers
//      right after the staging barrier, so its global latency hides under
//      this tile's QK/exp/PV compute instead of being serially exposed.
//  (3) s_setprio(1) around MFMA clusters (blocks are mutually async here --
//      the regime where setprio measured +4-7%).
// LDS 38.9 KB; launch_bounds(512,6) -> 3 blocks/CU = 24 waves/CU (LDS fits).
// Writes UNNORMALIZED partial O (bf16) and row-sum l (fp32).
// No online max: q,k >= 0 post-relu => exp safe in fp32.
// ---------------------------------------------------------------------------
__global__ __launch_bounds__(512, 6) void attn_kernel(
    const unsigned short* __restrict__ q_hi, const unsigned short* __restrict__ q_lo,
    const unsigned short* __restrict__ k_bf, const unsigned short* __restrict__ vt_g,
    unsigned short* __restrict__ pOb, float* __restrict__ pL)
{
    __shared__ __align__(16) unsigned short kt[64][72];      // [key][dim]
    __shared__ __align__(16) unsigned short vt[64][72];      // [dim][key]  (V^T)
    __shared__ __align__(16) unsigned short pt[8][16][40];   // per-wave P [q][key half]

    const int tid  = threadIdx.x;
    const int lane = tid & 63;
    const int w    = tid >> 6;           // 0..7
    const int quad = lane >> 4;
    const int l15  = lane & 15;
    const int ck   = blockIdx.y;         // key chunk (512 keys)
    const int b    = blockIdx.z;
    const int q0   = blockIdx.x * 128;   // within batch

    // Q fragments (A layout: m=lane&15, k=quad*8+j), split hi/lo
    const size_t qoff = ((size_t)b * 4096 + q0 + w * 16 + l15) * 64 + quad * 8;
    s16x8 qh0 = *(const s16x8*)(q_hi + qoff);
    s16x8 qh1 = *(const s16x8*)(q_hi + qoff + 32);
    s16x8 ql0 = *(const s16x8*)(q_lo + qoff);
    s16x8 ql1 = *(const s16x8*)(q_lo + qoff + 32);

    fx4 accO[4];
    #pragma unroll
    for (int nt = 0; nt < 4; nt++) accO[nt] = (fx4){0.f, 0.f, 0.f, 0.f};
    float lsum[4] = {0.f, 0.f, 0.f, 0.f};

    const unsigned short* kgb = k_bf + (size_t)b * 4096 * 64;  // [s][64]
    const unsigned short* vgb = vt_g + (size_t)b * 64 * 4096;  // [d][s]

    // staging: 512 threads, one 16B chunk each covers the full 64x64 tile
    const int srow = tid >> 3;        // 0..63
    const int soff = (tid & 7) * 8;

    // prologue prefetch of tile it0 into registers
    const int it0 = ck * 8;
    s16x8 nk = *(const s16x8*)(kgb + (size_t)it0 * 4096 + (size_t)srow * 64 + soff);
    s16x8 nv = *(const s16x8*)(vgb + (size_t)srow * 4096 + it0 * 64 + soff);

    for (int it = it0; it < it0 + 8; it++) {
        // regs -> LDS (prev iter's trailing barrier guarantees readers done)
        *(s16x8*)&kt[srow][soff] = nk;
        *(s16x8*)&vt[srow][soff] = nv;
        __syncthreads();
        // issue next tile's loads now; latency hides under compute below
        if (it + 1 < it0 + 8) {
            nk = *(const s16x8*)(kgb + (size_t)(it + 1) * 4096 + (size_t)srow * 64 + soff);
            nv = *(const s16x8*)(vgb + (size_t)srow * 4096 + (it + 1) * 64 + soff);
        }

        #pragma unroll
        for (int kh = 0; kh < 2; kh++) {
            // S = Q K^T for 32-key half (hi/lo compensated)
            #pragma unroll
            for (int nt2 = 0; nt2 < 2; nt2++) {
                int key = kh * 32 + nt2 * 16 + l15;
                s16x8 k0 = *(const s16x8*)&kt[key][quad * 8];
                s16x8 k1 = *(const s16x8*)&kt[key][32 + quad * 8];
                fx4 sc = (fx4){0.f, 0.f, 0.f, 0.f};
                __builtin_amdgcn_s_setprio(1);
                sc = __builtin_amdgcn_mfma_f32_16x16x32_bf16(qh0, k0, sc, 0, 0, 0);
                sc = __builtin_amdgcn_mfma_f32_16x16x32_bf16(ql0, k0, sc, 0, 0, 0);
                sc = __builtin_amdgcn_mfma_f32_16x16x32_bf16(qh1, k1, sc, 0, 0, 0);
                sc = __builtin_amdgcn_mfma_f32_16x16x32_bf16(ql1, k1, sc, 0, 0, 0);
                __builtin_amdgcn_s_setprio(0);
                // P = exp(S) -> bf16 -> wave-private LDS (C -> A layout)
                #pragma unroll
                for (int r = 0; r < 4; r++) {
                    float p = __builtin_amdgcn_exp2f(sc[r] * LOG2E);
                    unsigned short pb = f2bf(p);
                    lsum[r] += bf2f(pb);   // denominator matches rounded numerator
                    pt[w][quad * 4 + r][nt2 * 16 + l15] = pb;
                }
            }
            // O += P_half V_half  (k=32 exactly fills one MFMA)
            s16x8 pa = *(const s16x8*)&pt[w][l15][quad * 8];
            __builtin_amdgcn_s_setprio(1);
            #pragma unroll
            for (int nt = 0; nt < 4; nt++) {
                s16x8 vf = *(const s16x8*)&vt[nt * 16 + l15][kh * 32 + quad * 8];
                accO[nt] = __builtin_amdgcn_mfma_f32_16x16x32_bf16(pa, vf, accO[nt], 0, 0, 0);
            }
            __builtin_amdgcn_s_setprio(0);
        }
        __syncthreads();
    }

    // reduce row-sums across the 16 lanes sharing each row group
    #pragma unroll
    for (int r = 0; r < 4; r++) {
        float v = lsum[r];
        #pragma unroll
        for (int o = 1; o < 16; o <<= 1) v += __shfl_xor(v, o);
        lsum[r] = v;
    }
    // write partials: pOb[ck][b*4096+q][64] (bf16), pL[ck][b*4096+q] (fp32)
    #pragma unroll
    for (int r = 0; r < 4; r++) {
        int qrow = q0 + w * 16 + quad * 4 + r;
        size_t grow = (size_t)b * 4096 + qrow;
        #pragma unroll
        for (int nt = 0; nt < 4; nt++)
            pOb[((size_t)ck * 16384 + grow) * 64 + nt * 16 + l15] = f2bf(accO[nt][r]);
        if (l15 == 0)
            pL[(size_t)ck * 16384 + grow] = lsum[r];
    }
}

// ---------------------------------------------------------------------------
// Kernel 4: combine partials: out = (sum_c pOb) * mask / (sum_c pL)  (unchanged)
// ---------------------------------------------------------------------------
__global__ __launch_bounds__(256) void combine_kernel(
    const unsigned short* __restrict__ pOb, const float* __restrict__ pL,
    const float* __restrict__ mask, float* __restrict__ out)
{
    int idx = blockIdx.x * 256 + threadIdx.x;   // 262144 = (b*4096+s)*16 + dgrp
    int q  = idx >> 4;
    int dg = idx & 15;
    fx4 s = (fx4){0.f, 0.f, 0.f, 0.f};
    float l = 0.f;
    #pragma unroll
    for (int c = 0; c < 8; c++) {
        u16x4 h = *(const u16x4*)(pOb + ((size_t)c * 16384 + q) * 64 + dg * 4);
        s.x += bf2f(h.x);
        s.y += bf2f(h.y);
        s.z += bf2f(h.z);
        s.w += bf2f(h.w);
        l += pL[(size_t)c * 16384 + q];
    }
    float scale = mask[q] / l;
    *(fx4*)(out + (size_t)q * 64 + dg * 4) = s * scale;
}

// ---------------------------------------------------------------------------
extern "C" void kernel_launch(void* const* d_in, const int* in_sizes, int n_in,
                              void* d_out, int out_size, void* d_ws, size_t ws_size,
                              hipStream_t stream)
{
    const float* X    = (const float*)d_in[0];
    const float* mask = (const float*)d_in[1];
    const float* Wq   = (const float*)d_in[2];
    const float* bq   = (const float*)d_in[3];
    const float* Wk   = (const float*)d_in[4];
    const float* bk   = (const float*)d_in[5];
    const float* Wv   = (const float*)d_in[6];
    const float* bv   = (const float*)d_in[7];
    float* out = (float*)d_out;

    char* ws = (char*)d_ws;
    unsigned short* q_hi  = (unsigned short*)(ws);                       // 2 MB
    unsigned short* q_lo  = (unsigned short*)(ws + (size_t)(2u << 20));  // 2 MB
    unsigned short* k_bf  = (unsigned short*)(ws + (size_t)(4u << 20));  // 2 MB
    unsigned short* vt_g  = (unsigned short*)(ws + (size_t)(6u << 20));  // 2 MB  [b][d][s]
    unsigned short* wt_hi = (unsigned short*)(ws + (size_t)(8u << 20));  // 384 KB
    unsigned short* wt_lo = (unsigned short*)(ws + (size_t)(8u << 20) + 393216);
    unsigned short* pOb   = (unsigned short*)(ws + (size_t)(9u << 20));  // 16 MB [8][16384][64] bf16
    float*          pL    = (float*)(ws + (size_t)(25u << 20));          // 512 KB [8][16384]

    hipLaunchKernelGGL(prep_w_kernel, dim3(3, 16), dim3(256), 0, stream,
                       Wq, Wk, Wv, wt_hi, wt_lo);
    hipLaunchKernelGGL(proj_kernel, dim3(768), dim3(512), 0, stream,
                       X, wt_hi, wt_lo, bq, bk, bv, q_hi, q_lo, k_bf, vt_g);
    hipLaunchKernelGGL(attn_kernel, dim3(32, 8, 4), dim3(512), 0, stream,
                       q_hi, q_lo, k_bf, vt_g, pOb, pL);
    hipLaunchKernelGGL(combine_kernel, dim3(1024), dim3(256), 0, stream,
                       pOb, pL, mask, out);
}

// Round 5
// 166.334 us; speedup vs baseline: 1.3838x; 1.0465x over previous
//
#include <hip/hip_runtime.h>

// B=4, S=4096, D_IN=1024, D_QK=D_V=64
// out = softmax(relu(XWq+bq) @ relu(XWk+bk)^T) @ relu(XWv+bv) * mask

typedef short s16x8 __attribute__((ext_vector_type(8)));   // 8 bf16 (4 VGPRs) MFMA frag
typedef float fx4   __attribute__((ext_vector_type(4)));   // MFMA accum frag
typedef unsigned short u16x4 __attribute__((ext_vector_type(4)));

#define LOG2E 1.4426950408889634f

__device__ __forceinline__ unsigned short f2bf(float x) {   // fp32 -> bf16 RTN
    unsigned int u = __float_as_uint(x);
    u += 0x7FFFu + ((u >> 16) & 1u);
    return (unsigned short)(u >> 16);
}
__device__ __forceinline__ float bf2f(unsigned short b) {
    return __uint_as_float(((unsigned int)b) << 16);
}

// ---------------------------------------------------------------------------
// Kernel 1: split W{q,k,v} [1024][64] fp32 into W^T hi/lo bf16 [3][64][1024].
// LDS tile-transpose; coalesced reads, contiguous 32 B runs along k going out.
// grid (3 y, 16 k-tiles) x 256.  (unchanged)
// ---------------------------------------------------------------------------
__global__ __launch_bounds__(256) void prep_w_kernel(
    const float* __restrict__ Wq, const float* __restrict__ Wk, const float* __restrict__ Wv,
    unsigned short* __restrict__ wt_hi, unsigned short* __restrict__ wt_lo)
{
    __shared__ __align__(16) unsigned short sh[64][72];   // [c][k_local]
    __shared__ __align__(16) unsigned short sl[64][72];

    const int y  = blockIdx.x;
    const int kt = blockIdx.y;
    const float* W = (y == 0) ? Wq : (y == 1) ? Wk : Wv;
    const int t  = threadIdx.x;

    const int kl = t >> 2;
    const int c0 = (t & 3) * 16;
    const float* src = W + (size_t)(kt * 64 + kl) * 64 + c0;
    #pragma unroll
    for (int j = 0; j < 4; j++) {
        fx4 v = *(const fx4*)(src + j * 4);
        #pragma unroll
        for (int i = 0; i < 4; i++) {
            float x = v[i];
            unsigned short h = f2bf(x);
            unsigned short l = f2bf(x - bf2f(h));
            sh[c0 + j * 4 + i][kl] = h;
            sl[c0 + j * 4 + i][kl] = l;
        }
    }
    __syncthreads();

    const int c  = t >> 2;
    const int k0 = (t & 3) * 16;
    size_t o = (size_t)(y * 64 + c) * 1024 + kt * 64 + k0;
    *(s16x8*)(wt_hi + o)     = *(const s16x8*)&sh[c][k0];
    *(s16x8*)(wt_hi + o + 8) = *(const s16x8*)&sh[c][k0 + 8];
    *(s16x8*)(wt_lo + o)     = *(const s16x8*)&sl[c][k0];
    *(s16x8*)(wt_lo + o + 8) = *(const s16x8*)&sl[c][k0 + 8];
}

// ---------------------------------------------------------------------------
// Kernel 2 (v6): FUSED q/k/v projection, B in LDS. Grid 256 (one 64-row
// m-tile per block, 1 block/CU), block 768 = 12 waves = 2 row-groups x
// 6 col-groups ({q,k,v} x 2 col-halves). Combines the two things rounds
// 0-4 proved separately:
//  - v4's fusion win: X converted to hi/lo bf16 ONCE per m-tile (v2 did it
//    3x in 3 separate blocks) -> conversion VALU /3.
//  - v2's staging win: W relayed global->reg(depth 2)->LDS, X depth 4 --
//    the compiler KEEPS these relays live (v2: proven at 47us); it refuses
//    global->reg ping-pong consumed by MFMA across barriers (v3/v4 lesson).
// 32x32 wave tiles: 16 LDS frag reads per 24 MFMAs (v2: 12/12) -> LDS read
// volume per MFMA 2/3 of v2. Per-CU-kc: ~256KB LDS ~ 2300cy + ~1100cy VALU
// vs v2's ~7050cy -> predict ~25us. LDS 73,728 B. 2 barriers/kc (v2
// structure). MFMA order per output identical to v2 => bit-identical.
// ---------------------------------------------------------------------------
__global__ __launch_bounds__(768, 3) void proj_kernel(
    const float* __restrict__ X,
    const unsigned short* __restrict__ wt_hi, const unsigned short* __restrict__ wt_lo,
    const float* __restrict__ bq, const float* __restrict__ bk, const float* __restrict__ bv,
    unsigned short* __restrict__ q_hi, unsigned short* __restrict__ q_lo,
    unsigned short* __restrict__ k_bf, unsigned short* __restrict__ vt_g)
{
    __shared__ __align__(16) unsigned short a_hi[64][72];    // X tile hi (+8 pad)
    __shared__ __align__(16) unsigned short a_lo[64][72];    // X tile lo
    __shared__ __align__(16) unsigned short bsh[192][72];    // W^T all-y hi [col][k]
    __shared__ __align__(16) unsigned short bsl[192][72];    // W^T all-y lo

    const int tid  = threadIdx.x;
    const int lane = tid & 63;
    const int w    = tid >> 6;      // 0..11
    const int quad = lane >> 4;
    const int l15  = lane & 15;
    const int rowg = w & 1;         // 32-row group
    const int colg = w >> 1;        // 0..5 = {q,k,v} x {col half}
    const int y    = colg >> 1;     // 0=q 1=k 2=v
    const int ch   = colg & 1;      // 32-col half within y

    const int m0 = blockIdx.x * 64;

    fx4 acc[2][2];                  // [sub 16 rows][nt 16 cols]
    #pragma unroll
    for (int i = 0; i < 2; i++)
        #pragma unroll
        for (int j = 0; j < 2; j++) acc[i][j] = (fx4){0.f, 0.f, 0.f, 0.f};

    // X staging: threads 0..511, 8 floats each (rows xrow, xrow+32)
    const int xrow = tid >> 4;        // 0..31 (tid<512)
    const int xoff = (tid & 15) * 4;
    const float* xb0 = X + (size_t)(m0 + xrow) * 1024 + xoff;
    const float* xb1 = X + (size_t)(m0 + xrow + 32) * 1024 + xoff;

    // W staging: all 768 threads, 32 B (hi) + 32 B (lo) each per kc
    const int wrow = tid >> 2;        // 0..191
    const int wk   = (tid & 3) * 16;  // k-offset (shorts)
    const size_t wb = (size_t)wrow * 1024 + wk;

    // register relays: X depth 4, W depth 2 (v2-proven pattern)
    fx4   xr[4][2];
    s16x8 wrh[2][2], wrl[2][2];
    if (tid < 512) {
        #pragma unroll
        for (int d = 0; d < 4; d++) {
            xr[d][0] = *(const fx4*)(xb0 + d * 64);
            xr[d][1] = *(const fx4*)(xb1 + d * 64);
        }
    }
    #pragma unroll
    for (int d = 0; d < 2; d++) {
        wrh[d][0] = *(const s16x8*)(wt_hi + wb + d * 64);
        wrh[d][1] = *(const s16x8*)(wt_hi + wb + d * 64 + 8);
        wrl[d][0] = *(const s16x8*)(wt_lo + wb + d * 64);
        wrl[d][1] = *(const s16x8*)(wt_lo + wb + d * 64 + 8);
    }

    #pragma unroll 4
    for (int kc = 0; kc < 16; kc++) {
        if (kc) __syncthreads();   // prev iter's LDS readers done
        if (tid < 512) {
            #pragma unroll
            for (int i = 0; i < 2; i++) {
                fx4 xv = xr[kc & 3][i];
                unsigned short h0 = f2bf(xv.x), h1 = f2bf(xv.y), h2 = f2bf(xv.z), h3 = f2bf(xv.w);
                unsigned short l0 = f2bf(xv.x - bf2f(h0)), l1 = f2bf(xv.y - bf2f(h1));
                unsigned short l2 = f2bf(xv.z - bf2f(h2)), l3 = f2bf(xv.w - bf2f(h3));
                *(u16x4*)&a_hi[xrow + i * 32][xoff] = (u16x4){h0, h1, h2, h3};
                *(u16x4*)&a_lo[xrow + i * 32][xoff] = (u16x4){l0, l1, l2, l3};
            }
        }
        *(s16x8*)&bsh[wrow][wk]     = wrh[kc & 1][0];
        *(s16x8*)&bsh[wrow][wk + 8] = wrh[kc & 1][1];
        *(s16x8*)&bsl[wrow][wk]     = wrl[kc & 1][0];
        *(s16x8*)&bsl[wrow][wk + 8] = wrl[kc & 1][1];
        __syncthreads();

        // refill relays (latency hides behind this iter's frag reads + MFMAs)
        if (tid < 512 && kc < 12) {
            xr[kc & 3][0] = *(const fx4*)(xb0 + (kc + 4) * 64);
            xr[kc & 3][1] = *(const fx4*)(xb1 + (kc + 4) * 64);
        }
        if (kc < 14) {
            wrh[kc & 1][0] = *(const s16x8*)(wt_hi + wb + (kc + 2) * 64);
            wrh[kc & 1][1] = *(const s16x8*)(wt_hi + wb + (kc + 2) * 64 + 8);
            wrl[kc & 1][0] = *(const s16x8*)(wt_lo + wb + (kc + 2) * 64);
            wrl[kc & 1][1] = *(const s16x8*)(wt_lo + wb + (kc + 2) * 64 + 8);
        }

        // A frags (32 rows: sub=0,1)
        s16x8 ah[2][2], al[2][2];
        #pragma unroll
        for (int sub = 0; sub < 2; sub++)
            #pragma unroll
            for (int ks = 0; ks < 2; ks++) {
                const int r = rowg * 32 + sub * 16 + l15;
                ah[sub][ks] = *(const s16x8*)&a_hi[r][ks * 32 + quad * 8];
                al[sub][ks] = *(const s16x8*)&a_lo[r][ks * 32 + quad * 8];
            }
        #pragma unroll
        for (int nt = 0; nt < 2; nt++) {
            const int br = colg * 32 + nt * 16 + l15;
            #pragma unroll
            for (int ks = 0; ks < 2; ks++) {
                s16x8 bh = *(const s16x8*)&bsh[br][ks * 32 + quad * 8];
                s16x8 bl = *(const s16x8*)&bsl[br][ks * 32 + quad * 8];
                #pragma unroll
                for (int sub = 0; sub < 2; sub++) {
                    acc[sub][nt] = __builtin_amdgcn_mfma_f32_16x16x32_bf16(ah[sub][ks], bh, acc[sub][nt], 0, 0, 0);
                    acc[sub][nt] = __builtin_amdgcn_mfma_f32_16x16x32_bf16(ah[sub][ks], bl, acc[sub][nt], 0, 0, 0);
                    acc[sub][nt] = __builtin_amdgcn_mfma_f32_16x16x32_bf16(al[sub][ks], bh, acc[sub][nt], 0, 0, 0);
                }
            }
        }
    }
    __syncthreads();   // all MFMA LDS reads done before vtr alias writes

    // epilogue: bias + relu; q -> hi/lo, k -> bf16, v -> transpose via LDS
    const float* bias = (y == 0) ? bq : (y == 1) ? bk : bv;
    const int b   = m0 >> 12;
    const int s0b = m0 & 4095;
    unsigned short* vtr = &a_hi[0][0];  // alias: [64 d][72]

    #pragma unroll
    for (int sub = 0; sub < 2; sub++)
        #pragma unroll
        for (int nt = 0; nt < 2; nt++) {
            const int col = ch * 32 + nt * 16 + l15;
            const float bb = bias[col];
            const int rloc = rowg * 32 + sub * 16 + quad * 4;
            #pragma unroll
            for (int r = 0; r < 4; r++) {
                float v = fmaxf(acc[sub][nt][r] + bb, 0.f);
                size_t grow = (size_t)(m0 + rloc + r);
                if (y == 0) {
                    unsigned short h = f2bf(v);
                    unsigned short l = f2bf(v - bf2f(h));
                    q_hi[grow * 64 + col] = h;
                    q_lo[grow * 64 + col] = l;
                } else if (y == 1) {
                    k_bf[grow * 64 + col] = f2bf(v);
                } else {
                    vtr[col * 72 + rloc + r] = f2bf(v);  // transpose via LDS
                }
            }
        }
    __syncthreads();   // v-waves' vtr writes visible to storing threads
    if (tid < 512) {
        int row = tid >> 3;          // d 0..63
        int off = (tid & 7) * 8;     // s chunk
        s16x8 vv = *(const s16x8*)&vtr[row * 72 + off];
        *(s16x8*)(vt_g + (size_t)(b * 64 + row) * 4096 + s0b + off) = vv;
    }
}

// ---------------------------------------------------------------------------
// Kernel 3 (v5): fused attention, KV-split. 128 q-rows per block (8 waves,
// grid 32 x 8 x 4 = 1024), T14 register prefetch of next K/V tile across the
// barrier, s_setprio around MFMA clusters. LDS 38.9 KB.
// Writes UNNORMALIZED partial O (bf16) and row-sum l (fp32).
// No online max: q,k >= 0 post-relu => exp safe in fp32.  (unchanged)
// ---------------------------------------------------------------------------
__global__ __launch_bounds__(512, 6) void attn_kernel(
    const unsigned short* __restrict__ q_hi, const unsigned short* __restrict__ q_lo,
    const unsigned short* __restrict__ k_bf, const unsigned short* __restrict__ vt_g,
    unsigned short* __restrict__ pOb, float* __restrict__ pL)
{
    __shared__ __align__(16) unsigned short kt[64][72];      // [key][dim]
    __shared__ __align__(16) unsigned short vt[64][72];      // [dim][key]  (V^T)
    __shared__ __align__(16) unsigned short pt[8][16][40];   // per-wave P [q][key half]

    const int tid  = threadIdx.x;
    const int lane = tid & 63;
    const int w    = tid >> 6;           // 0..7
    const int quad = lane >> 4;
    const int l15  = lane & 15;
    const int ck   = blockIdx.y;         // key chunk (512 keys)
    const int b    = blockIdx.z;
    const int q0   = blockIdx.x * 128;   // within batch

    // Q fragments (A layout: m=lane&15, k=quad*8+j), split hi/lo
    const size_t qoff = ((size_t)b * 4096 + q0 + w * 16 + l15) * 64 + quad * 8;
    s16x8 qh0 = *(const s16x8*)(q_hi + qoff);
    s16x8 qh1 = *(const s16x8*)(q_hi + qoff + 32);
    s16x8 ql0 = *(const s16x8*)(q_lo + qoff);
    s16x8 ql1 = *(const s16x8*)(q_lo + qoff + 32);

    fx4 accO[4];
    #pragma unroll
    for (int nt = 0; nt < 4; nt++) accO[nt] = (fx4){0.f, 0.f, 0.f, 0.f};
    float lsum[4] = {0.f, 0.f, 0.f, 0.f};

    const unsigned short* kgb = k_bf + (size_t)b * 4096 * 64;  // [s][64]
    const unsigned short* vgb = vt_g + (size_t)b * 64 * 4096;  // [d][s]

    // staging: 512 threads, one 16B chunk each covers the full 64x64 tile
    const int srow = tid >> 3;        // 0..63
    const int soff = (tid & 7) * 8;

    // prologue prefetch of tile it0 into registers
    const int it0 = ck * 8;
    s16x8 nk = *(const s16x8*)(kgb + (size_t)it0 * 4096 + (size_t)srow * 64 + soff);
    s16x8 nv = *(const s16x8*)(vgb + (size_t)srow * 4096 + it0 * 64 + soff);

    for (int it = it0; it < it0 + 8; it++) {
        // regs -> LDS (prev iter's trailing barrier guarantees readers done)
        *(s16x8*)&kt[srow][soff] = nk;
        *(s16x8*)&vt[srow][soff] = nv;
        __syncthreads();
        // issue next tile's loads now; latency hides under compute below
        if (it + 1 < it0 + 8) {
            nk = *(const s16x8*)(kgb + (size_t)(it + 1) * 4096 + (size_t)srow * 64 + soff);
            nv = *(const s16x8*)(vgb + (size_t)srow * 4096 + (it + 1) * 64 + soff);
        }

        #pragma unroll
        for (int kh = 0; kh < 2; kh++) {
            // S = Q K^T for 32-key half (hi/lo compensated)
            #pragma unroll
            for (int nt2 = 0; nt2 < 2; nt2++) {
                int key = kh * 32 + nt2 * 16 + l15;
                s16x8 k0 = *(const s16x8*)&kt[key][quad * 8];
                s16x8 k1 = *(const s16x8*)&kt[key][32 + quad * 8];
                fx4 sc = (fx4){0.f, 0.f, 0.f, 0.f};
                __builtin_amdgcn_s_setprio(1);
                sc = __builtin_amdgcn_mfma_f32_16x16x32_bf16(qh0, k0, sc, 0, 0, 0);
                sc = __builtin_amdgcn_mfma_f32_16x16x32_bf16(ql0, k0, sc, 0, 0, 0);
                sc = __builtin_amdgcn_mfma_f32_16x16x32_bf16(qh1, k1, sc, 0, 0, 0);
                sc = __builtin_amdgcn_mfma_f32_16x16x32_bf16(ql1, k1, sc, 0, 0, 0);
                __builtin_amdgcn_s_setprio(0);
                // P = exp(S) -> bf16 -> wave-private LDS (C -> A layout)
                #pragma unroll
                for (int r = 0; r < 4; r++) {
                    float p = __builtin_amdgcn_exp2f(sc[r] * LOG2E);
                    unsigned short pb = f2bf(p);
                    lsum[r] += bf2f(pb);   // denominator matches rounded numerator
                    pt[w][quad * 4 + r][nt2 * 16 + l15] = pb;
                }
            }
            // O += P_half V_half  (k=32 exactly fills one MFMA)
            s16x8 pa = *(const s16x8*)&pt[w][l15][quad * 8];
            __builtin_amdgcn_s_setprio(1);
            #pragma unroll
            for (int nt = 0; nt < 4; nt++) {
                s16x8 vf = *(const s16x8*)&vt[nt * 16 + l15][kh * 32 + quad * 8];
                accO[nt] = __builtin_amdgcn_mfma_f32_16x16x32_bf16(pa, vf, accO[nt], 0, 0, 0);
            }
            __builtin_amdgcn_s_setprio(0);
        }
        __syncthreads();
    }

    // reduce row-sums across the 16 lanes sharing each row group
    #pragma unroll
    for (int r = 0; r < 4; r++) {
        float v = lsum[r];
        #pragma unroll
        for (int o = 1; o < 16; o <<= 1) v += __shfl_xor(v, o);
        lsum[r] = v;
    }
    // write partials: pOb[ck][b*4096+q][64] (bf16), pL[ck][b*4096+q] (fp32)
    #pragma unroll
    for (int r = 0; r < 4; r++) {
        int qrow = q0 + w * 16 + quad * 4 + r;
        size_t grow = (size_t)b * 4096 + qrow;
        #pragma unroll
        for (int nt = 0; nt < 4; nt++)
            pOb[((size_t)ck * 16384 + grow) * 64 + nt * 16 + l15] = f2bf(accO[nt][r]);
        if (l15 == 0)
            pL[(size_t)ck * 16384 + grow] = lsum[r];
    }
}

// ---------------------------------------------------------------------------
// Kernel 4: combine partials: out = (sum_c pOb) * mask / (sum_c pL)  (unchanged)
// ---------------------------------------------------------------------------
__global__ __launch_bounds__(256) void combine_kernel(
    const unsigned short* __restrict__ pOb, const float* __restrict__ pL,
    const float* __restrict__ mask, float* __restrict__ out)
{
    int idx = blockIdx.x * 256 + threadIdx.x;   // 262144 = (b*4096+s)*16 + dgrp
    int q  = idx >> 4;
    int dg = idx & 15;
    fx4 s = (fx4){0.f, 0.f, 0.f, 0.f};
    float l = 0.f;
    #pragma unroll
    for (int c = 0; c < 8; c++) {
        u16x4 h = *(const u16x4*)(pOb + ((size_t)c * 16384 + q) * 64 + dg * 4);
        s.x += bf2f(h.x);
        s.y += bf2f(h.y);
        s.z += bf2f(h.z);
        s.w += bf2f(h.w);
        l += pL[(size_t)c * 16384 + q];
    }
    float scale = mask[q] / l;
    *(fx4*)(out + (size_t)q * 64 + dg * 4) = s * scale;
}

// ---------------------------------------------------------------------------
extern "C" void kernel_launch(void* const* d_in, const int* in_sizes, int n_in,
                              void* d_out, int out_size, void* d_ws, size_t ws_size,
                              hipStream_t stream)
{
    const float* X    = (const float*)d_in[0];
    const float* mask = (const float*)d_in[1];
    const float* Wq   = (const float*)d_in[2];
    const float* bq   = (const float*)d_in[3];
    const float* Wk   = (const float*)d_in[4];
    const float* bk   = (const float*)d_in[5];
    const float* Wv   = (const float*)d_in[6];
    const float* bv   = (const float*)d_in[7];
    float* out = (float*)d_out;

    char* ws = (char*)d_ws;
    unsigned short* q_hi  = (unsigned short*)(ws);                       // 2 MB
    unsigned short* q_lo  = (unsigned short*)(ws + (size_t)(2u << 20));  // 2 MB
    unsigned short* k_bf  = (unsigned short*)(ws + (size_t)(4u << 20));  // 2 MB
    unsigned short* vt_g  = (unsigned short*)(ws + (size_t)(6u << 20));  // 2 MB  [b][d][s]
    unsigned short* wt_hi = (unsigned short*)(ws + (size_t)(8u << 20));  // 384 KB
    unsigned short* wt_lo = (unsigned short*)(ws + (size_t)(8u << 20) + 393216);
    unsigned short* pOb   = (unsigned short*)(ws + (size_t)(9u << 20));  // 16 MB [8][16384][64] bf16
    float*          pL    = (float*)(ws + (size_t)(25u << 20));          // 512 KB [8][16384]

    hipLaunchKernelGGL(prep_w_kernel, dim3(3, 16), dim3(256), 0, stream,
                       Wq, Wk, Wv, wt_hi, wt_lo);
    hipLaunchKernelGGL(proj_kernel, dim3(256), dim3(768), 0, stream,
                       X, wt_hi, wt_lo, bq, bk, bv, q_hi, q_lo, k_bf, vt_g);
    hipLaunchKernelGGL(attn_kernel, dim3(32, 8, 4), dim3(512), 0, stream,
                       q_hi, q_lo, k_bf, vt_g, pOb, pL);
    hipLaunchKernelGGL(combine_kernel, dim3(1024), dim3(256), 0, stream,
                       pOb, pL, mask, out);
}